// Round 9
// baseline (267.860 us; speedup 1.0000x reference)
//
#include <hip/hip_runtime.h>
#include <hip/hip_bf16.h>

// B=4, S=1024, D=1024, H=16, HD=64 — tokens M=4096, feature K=1024
// fp32 in -> bf16 convert -> bf16 MFMA GEMMs (fp32 accum) -> fp32 out.
// p1: m97-structure 128x128 proj (mode-1 dispatched first to hide its 3x work).
// attn: barrier-free kv loop — K/V fragments loaded straight from global in
//       MFMA B-layout (keff rows / vt rows), XCD-local grid for L2 reuse.
// oproj: 64x64 tiles, 1024 blocks (4/CU) for latency hiding.

typedef __bf16 bf16x8 __attribute__((ext_vector_type(8)));
typedef __bf16 bf16x4 __attribute__((ext_vector_type(4)));
typedef float  f32x4  __attribute__((ext_vector_type(4)));

#define DMODEL 1024

#define ASYNC_LOAD16(gp, lp)                                                  \
    __builtin_amdgcn_global_load_lds(                                         \
        (const __attribute__((address_space(1))) unsigned int*)(gp),          \
        (__attribute__((address_space(3))) unsigned int*)(lp), 16, 0, 0)

// ---------------------------------------------------------------------------
// fp32 -> bf16 conversion: x (4M) + 6 weights (1M each); Wbar pre-scaled by
// 0.2 and Wbeat by 0.1 (folds the score-bias scales into the GEMM).
// ---------------------------------------------------------------------------
__global__ __launch_bounds__(256) void cvt_kernel(
    const float* __restrict__ x,
    const float* __restrict__ Wq, const float* __restrict__ Wk,
    const float* __restrict__ Wv, const float* __restrict__ Wbar,
    const float* __restrict__ Wbeat, const float* __restrict__ Wo,
    __bf16* __restrict__ dst)
{
    const int g = blockIdx.x * 256 + threadIdx.x;
    const size_t e = (size_t)g * 8;
    const int seg = (int)(e >> 20);
    const float* src; size_t off; float s = 1.0f;
    if (seg < 4)       { src = x;     off = e; }
    else if (seg == 4) { src = Wq;    off = e - ((size_t)4 << 20); }
    else if (seg == 5) { src = Wk;    off = e - ((size_t)5 << 20); }
    else if (seg == 6) { src = Wv;    off = e - ((size_t)6 << 20); }
    else if (seg == 7) { src = Wbar;  off = e - ((size_t)7 << 20); s = 0.2f; }
    else if (seg == 8) { src = Wbeat; off = e - ((size_t)8 << 20); s = 0.1f; }
    else               { src = Wo;    off = e - ((size_t)9 << 20); }
    const float4 a = *(const float4*)&src[off];
    const float4 b = *(const float4*)&src[off + 4];
    bf16x8 v;
    v[0] = (__bf16)(a.x * s); v[1] = (__bf16)(a.y * s);
    v[2] = (__bf16)(a.z * s); v[3] = (__bf16)(a.w * s);
    v[4] = (__bf16)(b.x * s); v[5] = (__bf16)(b.y * s);
    v[6] = (__bf16)(b.z * s); v[7] = (__bf16)(b.w * s);
    *(bf16x8*)&dst[e] = v;
}

// ---------------------------------------------------------------------------
// proj kernel (m97 structure): 128x128 tile, BK=32, global_load_lds w=16.
// blockIdx.y -> mode via lut {1,0,2}: mode-1 (3 GEMM-units) dispatched FIRST.
// mode 0: q    = (x@Wq^T + bq) * 0.125   -> qbuf (bf16, attn scale folded)
// mode 1: keff = x@Wk^T + gather_bar(x)@(0.2Wbar)^T + gather_beat(x)@(0.1Wbeat)^T
//                + combined bias         -> keffbuf (bf16)
// mode 2: vt   = (x@Wv^T + bv) stored TRANSPOSED [b, n, s] -> vtbuf (bf16)
// ---------------------------------------------------------------------------
__global__ __launch_bounds__(256) void proj_kernel(
    const __bf16* __restrict__ xb,
    const __bf16* __restrict__ Wqb, const __bf16* __restrict__ Wkb,
    const __bf16* __restrict__ Wvb, const __bf16* __restrict__ Wbarb,
    const __bf16* __restrict__ Wbeatb,
    const float* __restrict__ bq, const float* __restrict__ bk,
    const float* __restrict__ bv, const float* __restrict__ bbar,
    const float* __restrict__ bbeat,
    const int* __restrict__ bar_idx, const int* __restrict__ beat_idx,
    __bf16* __restrict__ qbuf, __bf16* __restrict__ keffbuf,
    __bf16* __restrict__ vtbuf)
{
    const int lut[3] = {1, 0, 2};
    const int mode = lut[blockIdx.y];
    const int tile = blockIdx.x;          // 256 tiles = 32 (m) x 8 (n)
    const int m0 = (tile >> 3) << 7;
    const int n0 = (tile & 7) << 7;

    __shared__ __align__(16) __bf16 Alds[128 * 32];   // no padding (m104)
    __shared__ __align__(16) __bf16 Blds[128 * 32];

    const int t    = threadIdx.x;
    const int w    = t >> 6;
    const int lane = t & 63;
    const int l15  = lane & 15;
    const int quad = lane >> 4;
    const int wm   = (w >> 1) << 6;
    const int wn   = (w & 1) << 6;
    const int srow = t >> 2;
    const int scol = (t & 3) * 8;

    const int nterms = (mode == 1) ? 3 : 1;

    f32x4 acc[4][4];
    for (int i = 0; i < 4; ++i)
        for (int j = 0; j < 4; ++j)
            acc[i][j] = {0.f, 0.f, 0.f, 0.f};

    for (int term = 0; term < nterms; ++term) {
        const __bf16* Wterm =
            (mode == 0) ? Wqb :
            (mode == 2) ? Wvb :
            (term == 0) ? Wkb : (term == 1) ? Wbarb : Wbeatb;

        int arow0, arow1;
        if (mode != 1 || term == 0) {
            arow0 = m0 + srow;
            arow1 = m0 + 64 + srow;
        } else {
            const int* gi = (term == 1) ? bar_idx : beat_idx;
            const int bbase = m0 & ~1023;            // batch start
            arow0 = bbase + gi[(m0 & 1023) + srow];
            arow1 = bbase + gi[(m0 & 1023) + 64 + srow];
        }
        const __bf16* gA0 = xb + (size_t)arow0 * DMODEL + scol;
        const __bf16* gA1 = xb + (size_t)arow1 * DMODEL + scol;
        const __bf16* gB0 = Wterm + (size_t)(n0 + srow) * DMODEL + scol;
        const __bf16* gB1 = Wterm + (size_t)(n0 + 64 + srow) * DMODEL + scol;
        __bf16* lA0 = &Alds[w * 512];
        __bf16* lA1 = &Alds[2048 + w * 512];
        __bf16* lB0 = &Blds[w * 512];
        __bf16* lB1 = &Blds[2048 + w * 512];

        for (int kk = 0; kk < 32; ++kk) {
            const int k0 = kk * 32;
            ASYNC_LOAD16(gA0 + k0, lA0);
            ASYNC_LOAD16(gA1 + k0, lA1);
            ASYNC_LOAD16(gB0 + k0, lB0);
            ASYNC_LOAD16(gB1 + k0, lB1);
            __syncthreads();

            bf16x8 af[4], bfr[4];
            for (int i = 0; i < 4; ++i)
                af[i] = *(const bf16x8*)&Alds[(wm + i * 16 + l15) * 32 + quad * 8];
            for (int j = 0; j < 4; ++j)
                bfr[j] = *(const bf16x8*)&Blds[(wn + j * 16 + l15) * 32 + quad * 8];

            for (int i = 0; i < 4; ++i)
                for (int j = 0; j < 4; ++j)
                    acc[i][j] = __builtin_amdgcn_mfma_f32_16x16x32_bf16(
                        af[i], bfr[j], acc[i][j], 0, 0, 0);
            __syncthreads();
        }
    }

    // epilogue: fp32 bias + store
    for (int j = 0; j < 4; ++j) {
        const int col = n0 + wn + j * 16 + l15;
        float bias;
        if (mode == 0)      bias = bq[col];
        else if (mode == 1) bias = bk[col] + 0.2f * bbar[col] + 0.1f * bbeat[col];
        else                bias = bv[col];

        for (int i = 0; i < 4; ++i) {
            const int rowbase = m0 + wm + i * 16 + quad * 4;
            if (mode == 2) {
                const int bb = rowbase >> 10;
                const int sb = rowbase & 1023;
                bf16x4 vv;
                for (int r = 0; r < 4; ++r) vv[r] = (__bf16)(acc[i][j][r] + bias);
                *(bf16x4*)&vtbuf[((size_t)(bb * 1024 + col)) * 1024 + sb] = vv;
            } else if (mode == 0) {
                for (int r = 0; r < 4; ++r)
                    qbuf[(size_t)(rowbase + r) * DMODEL + col] =
                        (__bf16)((acc[i][j][r] + bias) * 0.125f);  // attn scale
            } else {
                for (int r = 0; r < 4; ++r)
                    keffbuf[(size_t)(rowbase + r) * DMODEL + col] =
                        (__bf16)(acc[i][j][r] + bias);
            }
        }
    }
}

// ---------------------------------------------------------------------------
// out-proj: out = attn @ Wo^T + bo (fp32). 64x64 tile, 1024 blocks (4/CU).
// ---------------------------------------------------------------------------
__global__ __launch_bounds__(256) void oproj_kernel(
    const __bf16* __restrict__ attnb, const __bf16* __restrict__ Wob,
    const float* __restrict__ bo, float* __restrict__ outb)
{
    const int tile = blockIdx.x;          // 1024 = 64 (m) x 16 (n)
    const int m0 = (tile >> 4) << 6;
    const int n0 = (tile & 15) << 6;

    __shared__ __align__(16) __bf16 Alds[64 * 32];
    __shared__ __align__(16) __bf16 Blds[64 * 32];

    const int t    = threadIdx.x;
    const int w    = t >> 6;
    const int lane = t & 63;
    const int l15  = lane & 15;
    const int quad = lane >> 4;
    const int wm   = (w >> 1) << 5;   // 2x2 waves, wave tile 32x32
    const int wn   = (w & 1) << 5;
    const int srow = t >> 2;
    const int scol = (t & 3) * 8;

    const __bf16* gA = attnb + (size_t)(m0 + srow) * DMODEL + scol;
    const __bf16* gB = Wob + (size_t)(n0 + srow) * DMODEL + scol;
    __bf16* lA = &Alds[w * 512];
    __bf16* lB = &Blds[w * 512];

    f32x4 acc[2][2];
    for (int i = 0; i < 2; ++i)
        for (int j = 0; j < 2; ++j)
            acc[i][j] = {0.f, 0.f, 0.f, 0.f};

    for (int kk = 0; kk < 32; ++kk) {
        const int k0 = kk * 32;
        ASYNC_LOAD16(gA + k0, lA);
        ASYNC_LOAD16(gB + k0, lB);
        __syncthreads();

        bf16x8 af[2], bfr[2];
        for (int i = 0; i < 2; ++i)
            af[i] = *(const bf16x8*)&Alds[(wm + i * 16 + l15) * 32 + quad * 8];
        for (int j = 0; j < 2; ++j)
            bfr[j] = *(const bf16x8*)&Blds[(wn + j * 16 + l15) * 32 + quad * 8];

        for (int i = 0; i < 2; ++i)
            for (int j = 0; j < 2; ++j)
                acc[i][j] = __builtin_amdgcn_mfma_f32_16x16x32_bf16(
                    af[i], bfr[j], acc[i][j], 0, 0, 0);
        __syncthreads();
    }

    for (int j = 0; j < 2; ++j) {
        const int col = n0 + wn + j * 16 + l15;
        const float bias = bo[col];
        for (int i = 0; i < 2; ++i) {
            const int rowbase = m0 + wm + i * 16 + quad * 4;
            for (int r = 0; r < 4; ++r)
                outb[(size_t)(rowbase + r) * DMODEL + col] = acc[i][j][r] + bias;
        }
    }
}

// ---------------------------------------------------------------------------
// flash attention, barrier-free kv loop. One block per (bh, 64 q-rows).
// K fragments (B[kv][d]) come straight from keff rows; V fragments
// (B[d][kv]) straight from vt rows — no K/V LDS, no __syncthreads.
// Grid x=bh, y=qt: all qt-blocks of one (b,h) share an XCD (linear ids
// differ by 64 == 0 mod 8) -> K/V live in that XCD's L2.
// Shift-free softmax (bounded scores); rowsum via ones-MFMA; q pre-scaled.
// ---------------------------------------------------------------------------
__global__ __launch_bounds__(256) void attn_kernel(
    const __bf16* __restrict__ qbuf, const __bf16* __restrict__ keffbuf,
    const __bf16* __restrict__ vtbuf, __bf16* __restrict__ attnbuf)
{
    const int bh = blockIdx.x;
    const int b  = bh >> 4;
    const int h  = bh & 15;
    const int qt = blockIdx.y;
    const int q0 = qt * 64;

    __shared__ __align__(16) __bf16 Plds[4][16][72];  // per-wave P only

    const int t    = threadIdx.x;
    const int w    = t >> 6;
    const int lane = t & 63;
    const int l15  = lane & 15;
    const int quad = lane >> 4;

    const __bf16* qbase =
        qbuf + (size_t)(b * 1024 + q0 + w * 16 + l15) * DMODEL + h * 64;
    bf16x8 qf0 = *(const bf16x8*)&qbase[quad * 8];
    bf16x8 qf1 = *(const bf16x8*)&qbase[32 + quad * 8];

    bf16x8 ones;
    for (int i = 0; i < 8; ++i) ones[i] = (__bf16)1.0f;

    f32x4 o[4];
    for (int i = 0; i < 4; ++i) o[i] = {0.f, 0.f, 0.f, 0.f};
    f32x4 lacc = {0.f, 0.f, 0.f, 0.f};

    // K rows: keff[b*1024 + kv][h*64 + d];  V rows: vt[b*1024 + h*64 + d][s=kv]
    const __bf16* kb = keffbuf + (size_t)(b * 1024) * DMODEL + h * 64;
    const __bf16* vb = vtbuf + (size_t)(b * 1024 + h * 64) * 1024;

    for (int j = 0; j <= qt; ++j) {
        // S = Q K^T : B-frag rows direct from global (L2-resident)
        f32x4 sc[4];
        for (int nt = 0; nt < 4; ++nt) {
            const __bf16* kr = kb + (size_t)(j * 64 + nt * 16 + l15) * DMODEL;
            bf16x8 kf0 = *(const bf16x8*)&kr[quad * 8];
            bf16x8 kf1 = *(const bf16x8*)&kr[32 + quad * 8];
            sc[nt] = {0.f, 0.f, 0.f, 0.f};
            sc[nt] = __builtin_amdgcn_mfma_f32_16x16x32_bf16(qf0, kf0, sc[nt], 0, 0, 0);
            sc[nt] = __builtin_amdgcn_mfma_f32_16x16x32_bf16(qf1, kf1, sc[nt], 0, 0, 0);
        }

        // causal mask (diagonal tile only): -1e30 -> exp underflows to 0
        if (j == qt) {
            const int qrow_base = q0 + w * 16 + quad * 4;
            for (int nt = 0; nt < 4; ++nt) {
                const int kcol = j * 64 + nt * 16 + l15;
                for (int r = 0; r < 4; ++r)
                    if (kcol > qrow_base + r) sc[nt][r] = -1e30f;
            }
        }

        // shift-free exp (scores bounded << 88)
        for (int nt = 0; nt < 4; ++nt)
            for (int r = 0; r < 4; ++r)
                sc[nt][r] = __expf(sc[nt][r]);

        // P -> per-wave LDS (C-layout), read back as A-layout frags
        for (int nt = 0; nt < 4; ++nt)
            for (int r = 0; r < 4; ++r)
                Plds[w][quad * 4 + r][nt * 16 + l15] = (__bf16)sc[nt][r];
        asm volatile("s_waitcnt lgkmcnt(0)" ::: "memory");

        bf16x8 pf0 = *(const bf16x8*)&Plds[w][l15][quad * 8];
        bf16x8 pf1 = *(const bf16x8*)&Plds[w][l15][32 + quad * 8];

        // row-sum via ones-MFMA (replicated over lanes, no shuffles)
        lacc = __builtin_amdgcn_mfma_f32_16x16x32_bf16(pf0, ones, lacc, 0, 0, 0);
        lacc = __builtin_amdgcn_mfma_f32_16x16x32_bf16(pf1, ones, lacc, 0, 0, 0);

        // O += P V : B-frag rows direct from vt (transposed V)
        for (int nd = 0; nd < 4; ++nd) {
            const __bf16* vr = vb + (size_t)(nd * 16 + l15) * 1024 + j * 64;
            bf16x8 vf0 = *(const bf16x8*)&vr[quad * 8];
            bf16x8 vf1 = *(const bf16x8*)&vr[32 + quad * 8];
            o[nd] = __builtin_amdgcn_mfma_f32_16x16x32_bf16(pf0, vf0, o[nd], 0, 0, 0);
            o[nd] = __builtin_amdgcn_mfma_f32_16x16x32_bf16(pf1, vf1, o[nd], 0, 0, 0);
        }
    }

    float rinv[4];
    for (int r = 0; r < 4; ++r) rinv[r] = 1.0f / lacc[r];
    for (int nd = 0; nd < 4; ++nd) {
        for (int r = 0; r < 4; ++r) {
            const int row = q0 + w * 16 + quad * 4 + r;
            attnbuf[(size_t)(b * 1024 + row) * DMODEL + h * 64 + nd * 16 + l15] =
                (__bf16)(o[nd][r] * rinv[r]);
        }
    }
}

extern "C" void kernel_launch(void* const* d_in, const int* in_sizes, int n_in,
                              void* d_out, int out_size, void* d_ws, size_t ws_size,
                              hipStream_t stream) {
    const float* x     = (const float*)d_in[0];
    const int* bar     = (const int*)d_in[2];
    const int* beat    = (const int*)d_in[3];
    const float* Wq    = (const float*)d_in[4];
    const float* bq    = (const float*)d_in[5];
    const float* Wk    = (const float*)d_in[6];
    const float* bk    = (const float*)d_in[7];
    const float* Wv    = (const float*)d_in[8];
    const float* bv    = (const float*)d_in[9];
    const float* Wbar  = (const float*)d_in[10];
    const float* bbar  = (const float*)d_in[11];
    const float* Wbeat = (const float*)d_in[12];
    const float* bbeat = (const float*)d_in[13];
    const float* Wo    = (const float*)d_in[14];
    const float* bo    = (const float*)d_in[15];

    const size_t M1 = (size_t)1 << 20;
    __bf16* xb     = (__bf16*)d_ws;       // 4M
    __bf16* Wqb    = xb + 4 * M1;         // 6 x 1M weights
    __bf16* Wkb    = Wqb + M1;
    __bf16* Wvb    = Wkb + M1;
    __bf16* Wbarb  = Wvb + M1;
    __bf16* Wbeatb = Wbarb + M1;
    __bf16* Wob    = Wbeatb + M1;
    __bf16* qbuf   = Wob + M1;            // 4M
    __bf16* keff   = qbuf + 4 * M1;       // 4M
    __bf16* vt     = keff + 4 * M1;       // 4M
    __bf16* attn   = vt + 4 * M1;         // 4M
    float*  outb   = (float*)d_out;

    cvt_kernel<<<5120, 256, 0, stream>>>(x, Wq, Wk, Wv, Wbar, Wbeat, Wo, xb);

    proj_kernel<<<dim3(256, 3), 256, 0, stream>>>(
        xb, Wqb, Wkb, Wvb, Wbarb, Wbeatb,
        bq, bk, bv, bbar, bbeat, bar, beat,
        qbuf, keff, vt);

    attn_kernel<<<dim3(64, 16), 256, 0, stream>>>(qbuf, keff, vt, attn);

    oproj_kernel<<<1024, 256, 0, stream>>>(attn, Wob, bo, outb);
}

// Round 10
// 250.101 us; speedup vs baseline: 1.0710x; 1.0710x over previous
//
#include <hip/hip_runtime.h>
#include <hip/hip_bf16.h>

// B=4, S=1024, D=1024, H=16, HD=64 — tokens M=4096, feature K=1024
// fp32 in -> bf16 convert -> bf16 MFMA GEMMs (fp32 accum) -> fp32 out.
// p1/oproj: R8-proven kernels (verbatim). attn: NEW balanced paired q-tiles
// (k and 15-k per block -> constant 17 kv-tile computations per block, zero
// causal tail), barrier-free, K/V loads shared between the two tiles.

typedef __bf16 bf16x8 __attribute__((ext_vector_type(8)));
typedef __bf16 bf16x4 __attribute__((ext_vector_type(4)));
typedef float  f32x4  __attribute__((ext_vector_type(4)));

#define DMODEL 1024

#define ASYNC_LOAD16(gp, lp)                                                  \
    __builtin_amdgcn_global_load_lds(                                         \
        (const __attribute__((address_space(1))) unsigned int*)(gp),          \
        (__attribute__((address_space(3))) unsigned int*)(lp), 16, 0, 0)

// ---------------------------------------------------------------------------
// fp32 -> bf16 conversion: x (4M) + 6 weights (1M each); Wbar pre-scaled by
// 0.2 and Wbeat by 0.1 (folds the score-bias scales into the GEMM).
// ---------------------------------------------------------------------------
__global__ __launch_bounds__(256) void cvt_kernel(
    const float* __restrict__ x,
    const float* __restrict__ Wq, const float* __restrict__ Wk,
    const float* __restrict__ Wv, const float* __restrict__ Wbar,
    const float* __restrict__ Wbeat, const float* __restrict__ Wo,
    __bf16* __restrict__ dst)
{
    const int g = blockIdx.x * 256 + threadIdx.x;
    const size_t e = (size_t)g * 8;
    const int seg = (int)(e >> 20);
    const float* src; size_t off; float s = 1.0f;
    if (seg < 4)       { src = x;     off = e; }
    else if (seg == 4) { src = Wq;    off = e - ((size_t)4 << 20); }
    else if (seg == 5) { src = Wk;    off = e - ((size_t)5 << 20); }
    else if (seg == 6) { src = Wv;    off = e - ((size_t)6 << 20); }
    else if (seg == 7) { src = Wbar;  off = e - ((size_t)7 << 20); s = 0.2f; }
    else if (seg == 8) { src = Wbeat; off = e - ((size_t)8 << 20); s = 0.1f; }
    else               { src = Wo;    off = e - ((size_t)9 << 20); }
    const float4 a = *(const float4*)&src[off];
    const float4 b = *(const float4*)&src[off + 4];
    bf16x8 v;
    v[0] = (__bf16)(a.x * s); v[1] = (__bf16)(a.y * s);
    v[2] = (__bf16)(a.z * s); v[3] = (__bf16)(a.w * s);
    v[4] = (__bf16)(b.x * s); v[5] = (__bf16)(b.y * s);
    v[6] = (__bf16)(b.z * s); v[7] = (__bf16)(b.w * s);
    *(bf16x8*)&dst[e] = v;
}

// ---------------------------------------------------------------------------
// proj kernel (m97 structure, R8-verbatim): 128x128 tile, BK=32.
// mode 0: q (scale 0.125 folded) | mode 1: keff 3-term | mode 2: v^T
// ---------------------------------------------------------------------------
__global__ __launch_bounds__(256) void proj_kernel(
    const __bf16* __restrict__ xb, const __bf16* __restrict__ attnbuf,
    const __bf16* __restrict__ Wqb, const __bf16* __restrict__ Wkb,
    const __bf16* __restrict__ Wvb, const __bf16* __restrict__ Wbarb,
    const __bf16* __restrict__ Wbeatb, const __bf16* __restrict__ Wob,
    const float* __restrict__ bq, const float* __restrict__ bk,
    const float* __restrict__ bv, const float* __restrict__ bbar,
    const float* __restrict__ bbeat, const float* __restrict__ bo,
    const int* __restrict__ bar_idx, const int* __restrict__ beat_idx,
    __bf16* __restrict__ qbuf, __bf16* __restrict__ keffbuf,
    __bf16* __restrict__ vtbuf, float* __restrict__ outbuf,
    int mode_base)
{
    const int mode = mode_base + blockIdx.y;
    const int tile = blockIdx.x;          // 256 tiles = 32 (m) x 8 (n)
    const int m0 = (tile >> 3) << 7;
    const int n0 = (tile & 7) << 7;

    __shared__ __align__(16) __bf16 Alds[128 * 32];   // no padding (m104)
    __shared__ __align__(16) __bf16 Blds[128 * 32];

    const int t    = threadIdx.x;
    const int w    = t >> 6;
    const int lane = t & 63;
    const int l15  = lane & 15;
    const int quad = lane >> 4;
    const int wm   = (w >> 1) << 6;
    const int wn   = (w & 1) << 6;
    const int srow = t >> 2;
    const int scol = (t & 3) * 8;

    const __bf16* Aptr = (mode == 3) ? attnbuf : xb;
    const int nterms = (mode == 1) ? 3 : 1;

    f32x4 acc[4][4];
    for (int i = 0; i < 4; ++i)
        for (int j = 0; j < 4; ++j)
            acc[i][j] = {0.f, 0.f, 0.f, 0.f};

    for (int term = 0; term < nterms; ++term) {
        const __bf16* Wterm =
            (mode == 0) ? Wqb :
            (mode == 2) ? Wvb :
            (mode == 3) ? Wob :
            (term == 0) ? Wkb : (term == 1) ? Wbarb : Wbeatb;

        int arow0, arow1;
        if (mode != 1 || term == 0) {
            arow0 = m0 + srow;
            arow1 = m0 + 64 + srow;
        } else {
            const int* gi = (term == 1) ? bar_idx : beat_idx;
            const int bbase = m0 & ~1023;            // batch start
            arow0 = bbase + gi[(m0 & 1023) + srow];
            arow1 = bbase + gi[(m0 & 1023) + 64 + srow];
        }
        const __bf16* gA0 = Aptr + (size_t)arow0 * DMODEL + scol;
        const __bf16* gA1 = Aptr + (size_t)arow1 * DMODEL + scol;
        const __bf16* gB0 = Wterm + (size_t)(n0 + srow) * DMODEL + scol;
        const __bf16* gB1 = Wterm + (size_t)(n0 + 64 + srow) * DMODEL + scol;
        __bf16* lA0 = &Alds[w * 512];
        __bf16* lA1 = &Alds[2048 + w * 512];
        __bf16* lB0 = &Blds[w * 512];
        __bf16* lB1 = &Blds[2048 + w * 512];

        for (int kk = 0; kk < 32; ++kk) {
            const int k0 = kk * 32;
            ASYNC_LOAD16(gA0 + k0, lA0);
            ASYNC_LOAD16(gA1 + k0, lA1);
            ASYNC_LOAD16(gB0 + k0, lB0);
            ASYNC_LOAD16(gB1 + k0, lB1);
            __syncthreads();

            bf16x8 af[4], bfr[4];
            for (int i = 0; i < 4; ++i)
                af[i] = *(const bf16x8*)&Alds[(wm + i * 16 + l15) * 32 + quad * 8];
            for (int j = 0; j < 4; ++j)
                bfr[j] = *(const bf16x8*)&Blds[(wn + j * 16 + l15) * 32 + quad * 8];

            for (int i = 0; i < 4; ++i)
                for (int j = 0; j < 4; ++j)
                    acc[i][j] = __builtin_amdgcn_mfma_f32_16x16x32_bf16(
                        af[i], bfr[j], acc[i][j], 0, 0, 0);
            __syncthreads();
        }
    }

    // epilogue: fp32 bias + store
    for (int j = 0; j < 4; ++j) {
        const int col = n0 + wn + j * 16 + l15;
        float bias;
        if (mode == 0)      bias = bq[col];
        else if (mode == 1) bias = bk[col] + 0.2f * bbar[col] + 0.1f * bbeat[col];
        else if (mode == 2) bias = bv[col];
        else                bias = bo[col];

        for (int i = 0; i < 4; ++i) {
            const int rowbase = m0 + wm + i * 16 + quad * 4;
            if (mode == 2) {
                const int bb = rowbase >> 10;
                const int sb = rowbase & 1023;
                bf16x4 vv;
                for (int r = 0; r < 4; ++r) vv[r] = (__bf16)(acc[i][j][r] + bias);
                *(bf16x4*)&vtbuf[((size_t)(bb * 1024 + col)) * 1024 + sb] = vv;
            } else if (mode == 3) {
                for (int r = 0; r < 4; ++r)
                    outbuf[(size_t)(rowbase + r) * DMODEL + col] =
                        acc[i][j][r] + bias;
            } else if (mode == 0) {
                for (int r = 0; r < 4; ++r)
                    qbuf[(size_t)(rowbase + r) * DMODEL + col] =
                        (__bf16)((acc[i][j][r] + bias) * 0.125f);  // attn scale
            } else {
                for (int r = 0; r < 4; ++r)
                    keffbuf[(size_t)(rowbase + r) * DMODEL + col] =
                        (__bf16)(acc[i][j][r] + bias);
            }
        }
    }
}

// ---------------------------------------------------------------------------
// out-proj (R8-verbatim): out = attn @ Wo^T + bo (fp32). 64x128 tile,
// 512 blocks (2/CU).
// ---------------------------------------------------------------------------
__global__ __launch_bounds__(256) void oproj_kernel(
    const __bf16* __restrict__ attnb, const __bf16* __restrict__ Wob,
    const float* __restrict__ bo, float* __restrict__ outb)
{
    const int tile = blockIdx.x;          // 512 = 64 (m) x 8 (n)
    const int m0 = (tile >> 3) << 6;
    const int n0 = (tile & 7) << 7;

    __shared__ __align__(16) __bf16 Alds[64 * 32];
    __shared__ __align__(16) __bf16 Blds[128 * 32];

    const int t    = threadIdx.x;
    const int w    = t >> 6;
    const int lane = t & 63;
    const int l15  = lane & 15;
    const int quad = lane >> 4;
    const int wm   = (w >> 1) << 5;   // 2 m-waves x 2 n-waves
    const int wn   = (w & 1) << 6;
    const int srow = t >> 2;
    const int scol = (t & 3) * 8;

    const __bf16* gA  = attnb + (size_t)(m0 + srow) * DMODEL + scol;
    const __bf16* gB0 = Wob + (size_t)(n0 + srow) * DMODEL + scol;
    const __bf16* gB1 = Wob + (size_t)(n0 + 64 + srow) * DMODEL + scol;
    __bf16* lA  = &Alds[w * 512];
    __bf16* lB0 = &Blds[w * 512];
    __bf16* lB1 = &Blds[2048 + w * 512];

    f32x4 acc[2][4];
    for (int i = 0; i < 2; ++i)
        for (int j = 0; j < 4; ++j)
            acc[i][j] = {0.f, 0.f, 0.f, 0.f};

    for (int kk = 0; kk < 32; ++kk) {
        const int k0 = kk * 32;
        ASYNC_LOAD16(gA + k0, lA);
        ASYNC_LOAD16(gB0 + k0, lB0);
        ASYNC_LOAD16(gB1 + k0, lB1);
        __syncthreads();

        bf16x8 af[2], bfr[4];
        for (int i = 0; i < 2; ++i)
            af[i] = *(const bf16x8*)&Alds[(wm + i * 16 + l15) * 32 + quad * 8];
        for (int j = 0; j < 4; ++j)
            bfr[j] = *(const bf16x8*)&Blds[(wn + j * 16 + l15) * 32 + quad * 8];

        for (int i = 0; i < 2; ++i)
            for (int j = 0; j < 4; ++j)
                acc[i][j] = __builtin_amdgcn_mfma_f32_16x16x32_bf16(
                    af[i], bfr[j], acc[i][j], 0, 0, 0);
        __syncthreads();
    }

    for (int j = 0; j < 4; ++j) {
        const int col = n0 + wn + j * 16 + l15;
        const float bias = bo[col];
        for (int i = 0; i < 2; ++i) {
            const int rowbase = m0 + wm + i * 16 + quad * 4;
            for (int r = 0; r < 4; ++r)
                outb[(size_t)(rowbase + r) * DMODEL + col] = acc[i][j][r] + bias;
        }
    }
}

// ---------------------------------------------------------------------------
// flash attention, BALANCED paired q-tiles: block (bh, k) handles q-tiles
// A = [64k, 64k+63] and B = [64(15-k), ...+63]. kv loop j = 0..15-k covers B;
// A is active for j <= k and SHARES the K/V fragment loads. Total tile
// computations per block = (k+1) + (16-k) = 17 — constant, zero causal tail.
// Barrier-free (per-wave P round-trip only); shift-free softmax; rowsum via
// ones-MFMA; q pre-scaled by 0.125. K frags from keff rows, V from vt rows.
// ---------------------------------------------------------------------------
__global__ __launch_bounds__(256) void attn_kernel(
    const __bf16* __restrict__ qbuf, const __bf16* __restrict__ keffbuf,
    const __bf16* __restrict__ vtbuf, __bf16* __restrict__ attnbuf)
{
    const int bh = blockIdx.x;
    const int b  = bh >> 4;
    const int h  = bh & 15;
    const int k  = blockIdx.y;            // 0..7
    const int qA = k * 64;                // near tile (k+1 kv-tiles)
    const int qB = (15 - k) * 64;         // far tile (16-k kv-tiles)

    __shared__ __align__(16) __bf16 PldsA[4][16][72];
    __shared__ __align__(16) __bf16 PldsB[4][16][72];

    const int t    = threadIdx.x;
    const int w    = t >> 6;
    const int lane = t & 63;
    const int l15  = lane & 15;
    const int quad = lane >> 4;

    const __bf16* qbA =
        qbuf + (size_t)(b * 1024 + qA + w * 16 + l15) * DMODEL + h * 64;
    const __bf16* qbB =
        qbuf + (size_t)(b * 1024 + qB + w * 16 + l15) * DMODEL + h * 64;
    bf16x8 qfA0 = *(const bf16x8*)&qbA[quad * 8];
    bf16x8 qfA1 = *(const bf16x8*)&qbA[32 + quad * 8];
    bf16x8 qfB0 = *(const bf16x8*)&qbB[quad * 8];
    bf16x8 qfB1 = *(const bf16x8*)&qbB[32 + quad * 8];

    bf16x8 ones;
    for (int i = 0; i < 8; ++i) ones[i] = (__bf16)1.0f;

    f32x4 oA[4], oB[4];
    for (int i = 0; i < 4; ++i) { oA[i] = {0.f,0.f,0.f,0.f}; oB[i] = {0.f,0.f,0.f,0.f}; }
    f32x4 laccA = {0.f, 0.f, 0.f, 0.f};
    f32x4 laccB = {0.f, 0.f, 0.f, 0.f};

    const __bf16* kb = keffbuf + (size_t)(b * 1024) * DMODEL + h * 64;
    const __bf16* vb = vtbuf + (size_t)(b * 1024 + h * 64) * 1024;

    const int jend = 15 - k;
    for (int j = 0; j <= jend; ++j) {
        const bool dual = (j <= k);

        // shared K fragments (B-layout rows straight from keff)
        bf16x8 kf[4][2];
        for (int nt = 0; nt < 4; ++nt) {
            const __bf16* kr = kb + (size_t)(j * 64 + nt * 16 + l15) * DMODEL;
            kf[nt][0] = *(const bf16x8*)&kr[quad * 8];
            kf[nt][1] = *(const bf16x8*)&kr[32 + quad * 8];
        }

        // S = Q K^T for tile B (always) and tile A (when dual)
        f32x4 sB[4], sA[4];
        for (int nt = 0; nt < 4; ++nt) {
            sB[nt] = {0.f, 0.f, 0.f, 0.f};
            sB[nt] = __builtin_amdgcn_mfma_f32_16x16x32_bf16(qfB0, kf[nt][0], sB[nt], 0, 0, 0);
            sB[nt] = __builtin_amdgcn_mfma_f32_16x16x32_bf16(qfB1, kf[nt][1], sB[nt], 0, 0, 0);
        }
        if (dual) {
            for (int nt = 0; nt < 4; ++nt) {
                sA[nt] = {0.f, 0.f, 0.f, 0.f};
                sA[nt] = __builtin_amdgcn_mfma_f32_16x16x32_bf16(qfA0, kf[nt][0], sA[nt], 0, 0, 0);
                sA[nt] = __builtin_amdgcn_mfma_f32_16x16x32_bf16(qfA1, kf[nt][1], sA[nt], 0, 0, 0);
            }
        }

        // causal masks: B's diagonal is j == jend; A's is j == k
        if (j == jend) {
            const int rb = qB + w * 16 + quad * 4;
            for (int nt = 0; nt < 4; ++nt) {
                const int kcol = j * 64 + nt * 16 + l15;
                for (int r = 0; r < 4; ++r)
                    if (kcol > rb + r) sB[nt][r] = -1e30f;
            }
        }
        if (dual && j == k) {
            const int ra = qA + w * 16 + quad * 4;
            for (int nt = 0; nt < 4; ++nt) {
                const int kcol = j * 64 + nt * 16 + l15;
                for (int r = 0; r < 4; ++r)
                    if (kcol > ra + r) sA[nt][r] = -1e30f;
            }
        }

        // shift-free exp (scores bounded << 88; -1e30 underflows to 0)
        for (int nt = 0; nt < 4; ++nt)
            for (int r = 0; r < 4; ++r)
                sB[nt][r] = __expf(sB[nt][r]);
        if (dual)
            for (int nt = 0; nt < 4; ++nt)
                for (int r = 0; r < 4; ++r)
                    sA[nt][r] = __expf(sA[nt][r]);

        // V fragments issued early (global/vmcnt — unaffected by lgkm wait)
        bf16x8 vf[4][2];
        for (int nd = 0; nd < 4; ++nd) {
            const __bf16* vr = vb + (size_t)(nd * 16 + l15) * 1024 + j * 64;
            vf[nd][0] = *(const bf16x8*)&vr[quad * 8];
            vf[nd][1] = *(const bf16x8*)&vr[32 + quad * 8];
        }

        // P -> per-wave LDS (C-layout), read back as A-layout frags
        for (int nt = 0; nt < 4; ++nt)
            for (int r = 0; r < 4; ++r)
                PldsB[w][quad * 4 + r][nt * 16 + l15] = (__bf16)sB[nt][r];
        if (dual)
            for (int nt = 0; nt < 4; ++nt)
                for (int r = 0; r < 4; ++r)
                    PldsA[w][quad * 4 + r][nt * 16 + l15] = (__bf16)sA[nt][r];
        asm volatile("s_waitcnt lgkmcnt(0)" ::: "memory");

        bf16x8 pfB0 = *(const bf16x8*)&PldsB[w][l15][quad * 8];
        bf16x8 pfB1 = *(const bf16x8*)&PldsB[w][l15][32 + quad * 8];
        laccB = __builtin_amdgcn_mfma_f32_16x16x32_bf16(pfB0, ones, laccB, 0, 0, 0);
        laccB = __builtin_amdgcn_mfma_f32_16x16x32_bf16(pfB1, ones, laccB, 0, 0, 0);
        for (int nd = 0; nd < 4; ++nd) {
            oB[nd] = __builtin_amdgcn_mfma_f32_16x16x32_bf16(pfB0, vf[nd][0], oB[nd], 0, 0, 0);
            oB[nd] = __builtin_amdgcn_mfma_f32_16x16x32_bf16(pfB1, vf[nd][1], oB[nd], 0, 0, 0);
        }
        if (dual) {
            bf16x8 pfA0 = *(const bf16x8*)&PldsA[w][l15][quad * 8];
            bf16x8 pfA1 = *(const bf16x8*)&PldsA[w][l15][32 + quad * 8];
            laccA = __builtin_amdgcn_mfma_f32_16x16x32_bf16(pfA0, ones, laccA, 0, 0, 0);
            laccA = __builtin_amdgcn_mfma_f32_16x16x32_bf16(pfA1, ones, laccA, 0, 0, 0);
            for (int nd = 0; nd < 4; ++nd) {
                oA[nd] = __builtin_amdgcn_mfma_f32_16x16x32_bf16(pfA0, vf[nd][0], oA[nd], 0, 0, 0);
                oA[nd] = __builtin_amdgcn_mfma_f32_16x16x32_bf16(pfA1, vf[nd][1], oA[nd], 0, 0, 0);
            }
        }
    }

    // epilogue: normalize + store both tiles
    float rinvA[4], rinvB[4];
    for (int r = 0; r < 4; ++r) { rinvA[r] = 1.0f / laccA[r]; rinvB[r] = 1.0f / laccB[r]; }
    for (int nd = 0; nd < 4; ++nd) {
        for (int r = 0; r < 4; ++r) {
            const int rowA = qA + w * 16 + quad * 4 + r;
            const int rowB = qB + w * 16 + quad * 4 + r;
            const int col  = h * 64 + nd * 16 + l15;
            attnbuf[(size_t)(b * 1024 + rowA) * DMODEL + col] = (__bf16)(oA[nd][r] * rinvA[r]);
            attnbuf[(size_t)(b * 1024 + rowB) * DMODEL + col] = (__bf16)(oB[nd][r] * rinvB[r]);
        }
    }
}

extern "C" void kernel_launch(void* const* d_in, const int* in_sizes, int n_in,
                              void* d_out, int out_size, void* d_ws, size_t ws_size,
                              hipStream_t stream) {
    const float* x     = (const float*)d_in[0];
    const int* bar     = (const int*)d_in[2];
    const int* beat    = (const int*)d_in[3];
    const float* Wq    = (const float*)d_in[4];
    const float* bq    = (const float*)d_in[5];
    const float* Wk    = (const float*)d_in[6];
    const float* bk    = (const float*)d_in[7];
    const float* Wv    = (const float*)d_in[8];
    const float* bv    = (const float*)d_in[9];
    const float* Wbar  = (const float*)d_in[10];
    const float* bbar  = (const float*)d_in[11];
    const float* Wbeat = (const float*)d_in[12];
    const float* bbeat = (const float*)d_in[13];
    const float* Wo    = (const float*)d_in[14];
    const float* bo    = (const float*)d_in[15];

    const size_t M1 = (size_t)1 << 20;
    __bf16* xb     = (__bf16*)d_ws;       // 4M
    __bf16* Wqb    = xb + 4 * M1;         // 6 x 1M weights
    __bf16* Wkb    = Wqb + M1;
    __bf16* Wvb    = Wkb + M1;
    __bf16* Wbarb  = Wvb + M1;
    __bf16* Wbeatb = Wbarb + M1;
    __bf16* Wob    = Wbeatb + M1;
    __bf16* qbuf   = Wob + M1;            // 4M
    __bf16* keff   = qbuf + 4 * M1;       // 4M
    __bf16* vt     = keff + 4 * M1;       // 4M
    __bf16* attn   = vt + 4 * M1;         // 4M
    float*  outb   = (float*)d_out;

    cvt_kernel<<<5120, 256, 0, stream>>>(x, Wq, Wk, Wv, Wbar, Wbeat, Wo, xb);

    proj_kernel<<<dim3(256, 3), 256, 0, stream>>>(
        xb, attn, Wqb, Wkb, Wvb, Wbarb, Wbeatb, Wob,
        bq, bk, bv, bbar, bbeat, bo, bar, beat,
        qbuf, keff, vt, outb, 0);

    attn_kernel<<<dim3(64, 8), 256, 0, stream>>>(qbuf, keff, vt, attn);

    oproj_kernel<<<512, 256, 0, stream>>>(attn, Wob, bo, outb);
}